// Round 1
// baseline (702.856 us; speedup 1.0000x reference)
//
#include <hip/hip_runtime.h>

#define LB __launch_bounds__(256)

typedef __bf16 bf16x8 __attribute__((ext_vector_type(8)));
typedef float f32x4 __attribute__((ext_vector_type(4)));

constexpr int B = 2, S = 2048, D = 1024, H = 16, DK = 64;
constexpr int M = B * S;   // 4096 tokens
constexpr int K = D;       // 1024 inner dim for projections

__device__ __forceinline__ unsigned short f2bf(float f) {
    union { float f; unsigned u; } v; v.f = f;
    unsigned r = v.u + 0x7fffu + ((v.u >> 16) & 1u);
    return (unsigned short)(r >> 16);
}

// ---- fp32 -> bf16 convert, 4 elems/thread ----
__global__ LB void cvt_bf16(const float* __restrict__ src,
                            unsigned short* __restrict__ dst, int n) {
    int i = (blockIdx.x * 256 + threadIdx.x) * 4;
    if (i >= n) return;
    float4 f = *reinterpret_cast<const float4*>(src + i);
    ushort4 o;
    o.x = f2bf(f.x); o.y = f2bf(f.y); o.z = f2bf(f.z); o.w = f2bf(f.w);
    *reinterpret_cast<ushort4*>(dst + i) = o;
}

// ---- C = A[M,K] @ W[N,K]^T, one 16x16 tile per wave, bf16 out ----
// mode 0: out[b,h,s,dk]   (Q/K layout; scale applied pre-round)
// mode 1: out[b,h,dk,s]   (V transposed for PV B-operand)
__global__ LB void proj_gemm(const unsigned short* __restrict__ A,
                             const unsigned short* __restrict__ W,
                             unsigned short* __restrict__ out,
                             int mode, float scale) {
    int wid = blockIdx.x * 4 + (threadIdx.x >> 6);
    int lane = threadIdx.x & 63;
    int mt = wid >> 6;          // N/16 = 64 n-tiles
    int nt = wid & 63;
    int r = lane & 15, g = lane >> 4;
    const bf16x8* pa = reinterpret_cast<const bf16x8*>(A + (size_t)(mt * 16 + r) * K + g * 8);
    const bf16x8* pb = reinterpret_cast<const bf16x8*>(W + (size_t)(nt * 16 + r) * K + g * 8);
    f32x4 acc = {0.f, 0.f, 0.f, 0.f};
#pragma unroll 4
    for (int k0 = 0; k0 < K; k0 += 32) {
        acc = __builtin_amdgcn_mfma_f32_16x16x32_bf16(pa[0], pb[0], acc, 0, 0, 0);
        pa += 4; pb += 4;
    }
    int col = nt * 16 + r;
    int h = col >> 6, dk = col & 63;
#pragma unroll
    for (int j = 0; j < 4; ++j) {
        int row = mt * 16 + g * 4 + j;
        int b = row >> 11, s = row & (S - 1);
        unsigned short val = f2bf(acc[j] * scale);
        size_t idx;
        if (mode == 0) idx = ((size_t)(b * H + h) * S + s) * DK + dk;
        else           idx = ((size_t)(b * H + h) * DK + dk) * S + s;
        out[idx] = val;
    }
}

// ---- final projection: fp32 out to d_out ----
__global__ LB void out_gemm(const unsigned short* __restrict__ A,
                            const unsigned short* __restrict__ W,
                            float* __restrict__ out) {
    int wid = blockIdx.x * 4 + (threadIdx.x >> 6);
    int lane = threadIdx.x & 63;
    int mt = wid >> 6, nt = wid & 63;
    int r = lane & 15, g = lane >> 4;
    const bf16x8* pa = reinterpret_cast<const bf16x8*>(A + (size_t)(mt * 16 + r) * K + g * 8);
    const bf16x8* pb = reinterpret_cast<const bf16x8*>(W + (size_t)(nt * 16 + r) * K + g * 8);
    f32x4 acc = {0.f, 0.f, 0.f, 0.f};
#pragma unroll 4
    for (int k0 = 0; k0 < K; k0 += 32) {
        acc = __builtin_amdgcn_mfma_f32_16x16x32_bf16(pa[0], pb[0], acc, 0, 0, 0);
        pa += 4; pb += 4;
    }
    int col = nt * 16 + r;
#pragma unroll
    for (int j = 0; j < 4; ++j) {
        int row = mt * 16 + g * 4 + j;
        out[(size_t)row * D + col] = acc[j];
    }
}

// ---- causal flash attention ----
// q,k: [B,H,S,DK] bf16 (q pre-scaled by 0.125*log2e), vt: [B,H,DK,S] bf16
// ao: [B*S, D] bf16 (heads concatenated)
__global__ LB void flash_attn(const unsigned short* __restrict__ q,
                              const unsigned short* __restrict__ kmat,
                              const unsigned short* __restrict__ vt,
                              unsigned short* __restrict__ ao) {
    __shared__ unsigned short plds[4][16][40];   // per-wave P tile, padded stride
    int bid = blockIdx.x;                        // B*H*(S/64) = 1024
    int qblk = bid & 31;
    int h = (bid >> 5) & 15;
    int b = bid >> 9;
    int w = threadIdx.x >> 6, lane = threadIdx.x & 63;
    int r = lane & 15, g = lane >> 4;
    int qw = qblk * 64 + w * 16;                 // wave's first q row

    const unsigned short* qb_ = q    + (size_t)(b * H + h) * S * DK;
    const unsigned short* kb_ = kmat + (size_t)(b * H + h) * S * DK;
    const unsigned short* vb_ = vt   + (size_t)(b * H + h) * DK * S;

    bf16x8 aq0 = *reinterpret_cast<const bf16x8*>(qb_ + (qw + r) * DK + g * 8);
    bf16x8 aq1 = *reinterpret_cast<const bf16x8*>(qb_ + (qw + r) * DK + 32 + g * 8);

    float mrun[4], lrun[4];
    f32x4 acc[4];
#pragma unroll
    for (int j = 0; j < 4; ++j) { mrun[j] = -1e30f; lrun[j] = 0.f; }
#pragma unroll
    for (int t = 0; t < 4; ++t) acc[t] = f32x4{0.f, 0.f, 0.f, 0.f};

    int nk = qw + 16;                            // causal: keys 0..qw+15
    for (int kb = 0; kb < nk; kb += 32) {
        f32x4 s0 = {0.f,0.f,0.f,0.f}, s1 = {0.f,0.f,0.f,0.f};
        const bf16x8* kp0 = reinterpret_cast<const bf16x8*>(kb_ + (kb + r) * DK + g * 8);
        const bf16x8* kp1 = reinterpret_cast<const bf16x8*>(kb_ + (kb + 16 + r) * DK + g * 8);
        s0 = __builtin_amdgcn_mfma_f32_16x16x32_bf16(aq0, kp0[0], s0, 0, 0, 0);
        s0 = __builtin_amdgcn_mfma_f32_16x16x32_bf16(aq1, kp0[4], s0, 0, 0, 0);
        s1 = __builtin_amdgcn_mfma_f32_16x16x32_bf16(aq0, kp1[0], s1, 0, 0, 0);
        s1 = __builtin_amdgcn_mfma_f32_16x16x32_bf16(aq1, kp1[4], s1, 0, 0, 0);

        float p0[4], p1[4];
#pragma unroll
        for (int j = 0; j < 4; ++j) {
            int row = qw + g * 4 + j;
            bool ok0 = (kb + r) <= row;
            bool ok1 = (kb + 16 + r) <= row;
            float v0 = ok0 ? s0[j] : -1e30f;
            float v1 = ok1 ? s1[j] : -1e30f;
            float tm = fmaxf(v0, v1);
#pragma unroll
            for (int mb = 1; mb <= 8; mb <<= 1)
                tm = fmaxf(tm, __shfl_xor(tm, mb));
            float mnew = fmaxf(mrun[j], tm);
            float alpha = exp2f(mrun[j] - mnew);
            float e0 = ok0 ? exp2f(s0[j] - mnew) : 0.f;
            float e1 = ok1 ? exp2f(s1[j] - mnew) : 0.f;
            float ps = e0 + e1;
#pragma unroll
            for (int mb = 1; mb <= 8; mb <<= 1)
                ps += __shfl_xor(ps, mb);
            lrun[j] = lrun[j] * alpha + ps;
            mrun[j] = mnew;
            p0[j] = e0; p1[j] = e1;
#pragma unroll
            for (int t = 0; t < 4; ++t) acc[t][j] *= alpha;
        }
        // P: D-layout -> LDS -> A-layout
#pragma unroll
        for (int j = 0; j < 4; ++j) {
            plds[w][g * 4 + j][r]      = f2bf(p0[j]);
            plds[w][g * 4 + j][16 + r] = f2bf(p1[j]);
        }
        asm volatile("s_waitcnt lgkmcnt(0)" ::: "memory");
        bf16x8 pa = *reinterpret_cast<const bf16x8*>(&plds[w][r][g * 8]);
#pragma unroll
        for (int t = 0; t < 4; ++t) {
            const bf16x8* bv = reinterpret_cast<const bf16x8*>(
                vb_ + (size_t)(t * 16 + r) * S + kb + g * 8);
            acc[t] = __builtin_amdgcn_mfma_f32_16x16x32_bf16(pa, bv[0], acc[t], 0, 0, 0);
        }
    }
#pragma unroll
    for (int j = 0; j < 4; ++j) {
        float inv = 1.0f / lrun[j];
        int row = qw + g * 4 + j;
        size_t base = ((size_t)b * S + row) * D + h * DK;
#pragma unroll
        for (int t = 0; t < 4; ++t)
            ao[base + t * 16 + r] = f2bf(acc[t][j] * inv);
    }
}

extern "C" void kernel_launch(void* const* d_in, const int* in_sizes, int n_in,
                              void* d_out, int out_size, void* d_ws, size_t ws_size,
                              hipStream_t stream) {
    const float* x  = (const float*)d_in[0];
    const float* wq = (const float*)d_in[1];
    const float* wk = (const float*)d_in[2];
    const float* wv = (const float*)d_in[3];
    const float* wo = (const float*)d_in[4];
    char* ws = (char*)d_ws;
    unsigned short* xb  = (unsigned short*)(ws);
    unsigned short* wqb = (unsigned short*)(ws + (size_t)(8  << 20));
    unsigned short* wkb = (unsigned short*)(ws + (size_t)(10 << 20));
    unsigned short* wvb = (unsigned short*)(ws + (size_t)(12 << 20));
    unsigned short* wob = (unsigned short*)(ws + (size_t)(14 << 20));
    unsigned short* qb  = (unsigned short*)(ws + (size_t)(16 << 20));
    unsigned short* kb  = (unsigned short*)(ws + (size_t)(24 << 20));
    unsigned short* vtb = (unsigned short*)(ws + (size_t)(32 << 20));
    unsigned short* aob = (unsigned short*)(ws + (size_t)(40 << 20));

    cvt_bf16<<<4096, 256, 0, stream>>>(x,  xb,  M * D);
    cvt_bf16<<<1024, 256, 0, stream>>>(wq, wqb, D * D);
    cvt_bf16<<<1024, 256, 0, stream>>>(wk, wkb, D * D);
    cvt_bf16<<<1024, 256, 0, stream>>>(wv, wvb, D * D);
    cvt_bf16<<<1024, 256, 0, stream>>>(wo, wob, D * D);

    const float QSCALE = 0.125f * 1.44269504088896341f;  // fold 1/sqrt(dk) and log2(e)
    proj_gemm<<<4096, 256, 0, stream>>>(xb, wqb, qb,  0, QSCALE);
    proj_gemm<<<4096, 256, 0, stream>>>(xb, wkb, kb,  0, 1.0f);
    proj_gemm<<<4096, 256, 0, stream>>>(xb, wvb, vtb, 1, 1.0f);
    flash_attn<<<1024, 256, 0, stream>>>(qb, kb, vtb, aob);
    out_gemm<<<4096, 256, 0, stream>>>(aob, wob, (float*)d_out);
}

// Round 2
// 310.245 us; speedup vs baseline: 2.2655x; 2.2655x over previous
//
#include <hip/hip_runtime.h>

#define LB __launch_bounds__(256)

typedef __bf16 bf16x8 __attribute__((ext_vector_type(8)));
typedef float f32x4 __attribute__((ext_vector_type(4)));
typedef unsigned short ushort_t;

constexpr int B = 2, S = 2048, D = 1024, H = 16, DK = 64;
constexpr int M = B * S;   // 4096 tokens
constexpr int K = D;       // 1024 inner dim for projections

__device__ __forceinline__ unsigned short f2bf(float f) {
    union { float f; unsigned u; } v; v.f = f;
    unsigned r = v.u + 0x7fffu + ((v.u >> 16) & 1u);
    return (unsigned short)(r >> 16);
}

__device__ __forceinline__ void gld_lds16(const unsigned short* g, unsigned short* l) {
    __builtin_amdgcn_global_load_lds(
        (const __attribute__((address_space(1))) unsigned int*)g,
        (__attribute__((address_space(3))) unsigned int*)l, 16, 0, 0);
}

// ---- fp32 -> bf16 convert, 4 elems/thread ----
__global__ LB void cvt_bf16(const float* __restrict__ src,
                            unsigned short* __restrict__ dst, int n) {
    int i = (blockIdx.x * 256 + threadIdx.x) * 4;
    if (i >= n) return;
    float4 f = *reinterpret_cast<const float4*>(src + i);
    ushort4 o;
    o.x = f2bf(f.x); o.y = f2bf(f.y); o.z = f2bf(f.z); o.w = f2bf(f.w);
    *reinterpret_cast<ushort4*>(dst + i) = o;
}

// ---- fused QKV projection: C = x @ W^T for W in {wq,wk,wv} (blockIdx.y) ----
// 128x128 tile, BK=32, 4 waves (2x2), global_load_lds staging.
__global__ LB void gemm_qkv(const unsigned short* __restrict__ A,
                            const unsigned short* __restrict__ wqb,
                            const unsigned short* __restrict__ wkb,
                            const unsigned short* __restrict__ wvb,
                            unsigned short* __restrict__ qo,
                            unsigned short* __restrict__ ko,
                            unsigned short* __restrict__ vo) {
    __shared__ __align__(16) unsigned short lA[128 * 32];
    __shared__ __align__(16) unsigned short lB[128 * 32];
    const int z = blockIdx.y;
    const unsigned short* W = (z == 0) ? wqb : ((z == 1) ? wkb : wvb);
    int m0 = (blockIdx.x >> 3) * 128;
    int n0 = (blockIdx.x & 7) * 128;
    int t = threadIdx.x;
    int w = t >> 6, lane = t & 63;
    int r = lane & 15, g = lane >> 4;
    int wr = w >> 1, wc = w & 1;
    int rowT = t >> 2, colOff = (t & 3) * 8;   // staging row/col within tile

    f32x4 acc[4][4];
#pragma unroll
    for (int mi = 0; mi < 4; ++mi)
#pragma unroll
        for (int ni = 0; ni < 4; ++ni) acc[mi][ni] = f32x4{0.f, 0.f, 0.f, 0.f};

    for (int k0 = 0; k0 < K; k0 += 32) {
        gld_lds16(A + (size_t)(m0 + rowT) * K + k0 + colOff,      lA + (w * 64) * 8);
        gld_lds16(A + (size_t)(m0 + 64 + rowT) * K + k0 + colOff, lA + (256 + w * 64) * 8);
        gld_lds16(W + (size_t)(n0 + rowT) * K + k0 + colOff,      lB + (w * 64) * 8);
        gld_lds16(W + (size_t)(n0 + 64 + rowT) * K + k0 + colOff, lB + (256 + w * 64) * 8);
        __syncthreads();
        bf16x8 af[4], bfr[4];
#pragma unroll
        for (int mi = 0; mi < 4; ++mi)
            af[mi] = *reinterpret_cast<const bf16x8*>(&lA[(wr * 64 + mi * 16 + r) * 32 + g * 8]);
#pragma unroll
        for (int ni = 0; ni < 4; ++ni)
            bfr[ni] = *reinterpret_cast<const bf16x8*>(&lB[(wc * 64 + ni * 16 + r) * 32 + g * 8]);
#pragma unroll
        for (int mi = 0; mi < 4; ++mi)
#pragma unroll
            for (int ni = 0; ni < 4; ++ni)
                acc[mi][ni] = __builtin_amdgcn_mfma_f32_16x16x32_bf16(af[mi], bfr[ni], acc[mi][ni], 0, 0, 0);
        __syncthreads();
    }

    const float QSCALE = 0.125f * 1.44269504088896341f;
    float scale = (z == 0) ? QSCALE : 1.0f;
    unsigned short* dst = (z == 0) ? qo : ((z == 1) ? ko : vo);
#pragma unroll
    for (int mi = 0; mi < 4; ++mi)
#pragma unroll
        for (int ni = 0; ni < 4; ++ni)
#pragma unroll
            for (int j = 0; j < 4; ++j) {
                int row = m0 + wr * 64 + mi * 16 + g * 4 + j;
                int col = n0 + wc * 64 + ni * 16 + r;
                int b = row >> 11, s = row & (S - 1);
                int h = col >> 6, dk = col & 63;
                unsigned short val = f2bf(acc[mi][ni][j] * scale);
                if (z < 2) dst[((size_t)(b * H + h) * S + s) * DK + dk] = val;
                else       dst[((size_t)(b * H + h) * DK + dk) * S + s] = val;
            }
}

// ---- output projection: fp32 out, same 128x128 structure ----
__global__ LB void out_gemm(const unsigned short* __restrict__ A,
                            const unsigned short* __restrict__ W,
                            float* __restrict__ out) {
    __shared__ __align__(16) unsigned short lA[128 * 32];
    __shared__ __align__(16) unsigned short lB[128 * 32];
    int m0 = (blockIdx.x >> 3) * 128;
    int n0 = (blockIdx.x & 7) * 128;
    int t = threadIdx.x;
    int w = t >> 6, lane = t & 63;
    int r = lane & 15, g = lane >> 4;
    int wr = w >> 1, wc = w & 1;
    int rowT = t >> 2, colOff = (t & 3) * 8;

    f32x4 acc[4][4];
#pragma unroll
    for (int mi = 0; mi < 4; ++mi)
#pragma unroll
        for (int ni = 0; ni < 4; ++ni) acc[mi][ni] = f32x4{0.f, 0.f, 0.f, 0.f};

    for (int k0 = 0; k0 < K; k0 += 32) {
        gld_lds16(A + (size_t)(m0 + rowT) * K + k0 + colOff,      lA + (w * 64) * 8);
        gld_lds16(A + (size_t)(m0 + 64 + rowT) * K + k0 + colOff, lA + (256 + w * 64) * 8);
        gld_lds16(W + (size_t)(n0 + rowT) * K + k0 + colOff,      lB + (w * 64) * 8);
        gld_lds16(W + (size_t)(n0 + 64 + rowT) * K + k0 + colOff, lB + (256 + w * 64) * 8);
        __syncthreads();
        bf16x8 af[4], bfr[4];
#pragma unroll
        for (int mi = 0; mi < 4; ++mi)
            af[mi] = *reinterpret_cast<const bf16x8*>(&lA[(wr * 64 + mi * 16 + r) * 32 + g * 8]);
#pragma unroll
        for (int ni = 0; ni < 4; ++ni)
            bfr[ni] = *reinterpret_cast<const bf16x8*>(&lB[(wc * 64 + ni * 16 + r) * 32 + g * 8]);
#pragma unroll
        for (int mi = 0; mi < 4; ++mi)
#pragma unroll
            for (int ni = 0; ni < 4; ++ni)
                acc[mi][ni] = __builtin_amdgcn_mfma_f32_16x16x32_bf16(af[mi], bfr[ni], acc[mi][ni], 0, 0, 0);
        __syncthreads();
    }

#pragma unroll
    for (int mi = 0; mi < 4; ++mi)
#pragma unroll
        for (int ni = 0; ni < 4; ++ni)
#pragma unroll
            for (int j = 0; j < 4; ++j) {
                int row = m0 + wr * 64 + mi * 16 + g * 4 + j;
                int col = n0 + wc * 64 + ni * 16 + r;
                out[(size_t)row * D + col] = acc[mi][ni][j];
            }
}

// ---- causal flash attention: 64 keys/iter, one reduction pass per row ----
__global__ LB void flash_attn(const unsigned short* __restrict__ q,
                              const unsigned short* __restrict__ kmat,
                              const unsigned short* __restrict__ vt,
                              unsigned short* __restrict__ ao) {
    __shared__ unsigned short plds[4][16][72];   // per-wave P tile (64 keys + pad)
    int bid = blockIdx.x;                        // B*H*(S/64) = 1024
    int qblk = bid & 31;
    int h = (bid >> 5) & 15;
    int b = bid >> 9;
    int w = threadIdx.x >> 6, lane = threadIdx.x & 63;
    int r = lane & 15, g = lane >> 4;
    int qw = qblk * 64 + w * 16;

    const unsigned short* qb_ = q    + (size_t)(b * H + h) * S * DK;
    const unsigned short* kb_ = kmat + (size_t)(b * H + h) * S * DK;
    const unsigned short* vb_ = vt   + (size_t)(b * H + h) * DK * S;

    bf16x8 aq0 = *reinterpret_cast<const bf16x8*>(qb_ + (qw + r) * DK + g * 8);
    bf16x8 aq1 = *reinterpret_cast<const bf16x8*>(qb_ + (qw + r) * DK + 32 + g * 8);

    float mrun[4], lrun[4];
    f32x4 acc[4];
#pragma unroll
    for (int j = 0; j < 4; ++j) { mrun[j] = -1e30f; lrun[j] = 0.f; }
#pragma unroll
    for (int t = 0; t < 4; ++t) acc[t] = f32x4{0.f, 0.f, 0.f, 0.f};

    int nk = qw + 16;
    for (int kb = 0; kb < nk; kb += 64) {
        f32x4 sc[4];
#pragma unroll
        for (int t = 0; t < 4; ++t) {
            const bf16x8* kp = reinterpret_cast<const bf16x8*>(kb_ + (size_t)(kb + t * 16 + r) * DK + g * 8);
            f32x4 s = {0.f, 0.f, 0.f, 0.f};
            s = __builtin_amdgcn_mfma_f32_16x16x32_bf16(aq0, kp[0], s, 0, 0, 0);
            s = __builtin_amdgcn_mfma_f32_16x16x32_bf16(aq1, kp[4], s, 0, 0, 0);
            sc[t] = s;
        }
#pragma unroll
        for (int j = 0; j < 4; ++j) {
            int row = qw + g * 4 + j;
            bool ok[4];
            float e[4];
            float tm = -1e30f;
#pragma unroll
            for (int t = 0; t < 4; ++t) {
                ok[t] = (kb + t * 16 + r) <= row;
                float v = ok[t] ? sc[t][j] : -1e30f;
                e[t] = v;
                tm = fmaxf(tm, v);
            }
#pragma unroll
            for (int mb = 1; mb <= 8; mb <<= 1)
                tm = fmaxf(tm, __shfl_xor(tm, mb));
            float mnew = fmaxf(mrun[j], tm);
            float alpha = exp2f(mrun[j] - mnew);
            float ps = 0.f;
#pragma unroll
            for (int t = 0; t < 4; ++t) {
                e[t] = ok[t] ? exp2f(e[t] - mnew) : 0.f;
                ps += e[t];
            }
#pragma unroll
            for (int mb = 1; mb <= 8; mb <<= 1)
                ps += __shfl_xor(ps, mb);
            lrun[j] = lrun[j] * alpha + ps;
            mrun[j] = mnew;
#pragma unroll
            for (int t = 0; t < 4; ++t) acc[t][j] *= alpha;
#pragma unroll
            for (int t = 0; t < 4; ++t)
                plds[w][g * 4 + j][t * 16 + r] = f2bf(e[t]);
        }
        asm volatile("s_waitcnt lgkmcnt(0)" ::: "memory");
        bf16x8 pa0 = *reinterpret_cast<const bf16x8*>(&plds[w][r][g * 8]);
        bf16x8 pa1 = *reinterpret_cast<const bf16x8*>(&plds[w][r][32 + g * 8]);
#pragma unroll
        for (int t = 0; t < 4; ++t) {
            const bf16x8* bv0 = reinterpret_cast<const bf16x8*>(vb_ + (size_t)(t * 16 + r) * S + kb + g * 8);
            const bf16x8* bv1 = reinterpret_cast<const bf16x8*>(vb_ + (size_t)(t * 16 + r) * S + kb + 32 + g * 8);
            acc[t] = __builtin_amdgcn_mfma_f32_16x16x32_bf16(pa0, bv0[0], acc[t], 0, 0, 0);
            acc[t] = __builtin_amdgcn_mfma_f32_16x16x32_bf16(pa1, bv1[0], acc[t], 0, 0, 0);
        }
    }
#pragma unroll
    for (int j = 0; j < 4; ++j) {
        float inv = 1.0f / lrun[j];
        int row = qw + g * 4 + j;
        size_t base = ((size_t)b * S + row) * D + h * DK;
#pragma unroll
        for (int t = 0; t < 4; ++t)
            ao[base + t * 16 + r] = f2bf(acc[t][j] * inv);
    }
}

extern "C" void kernel_launch(void* const* d_in, const int* in_sizes, int n_in,
                              void* d_out, int out_size, void* d_ws, size_t ws_size,
                              hipStream_t stream) {
    const float* x  = (const float*)d_in[0];
    const float* wq = (const float*)d_in[1];
    const float* wk = (const float*)d_in[2];
    const float* wv = (const float*)d_in[3];
    const float* wo = (const float*)d_in[4];
    char* ws = (char*)d_ws;
    unsigned short* xb  = (unsigned short*)(ws);
    unsigned short* wqb = (unsigned short*)(ws + (size_t)(8  << 20));
    unsigned short* wkb = (unsigned short*)(ws + (size_t)(10 << 20));
    unsigned short* wvb = (unsigned short*)(ws + (size_t)(12 << 20));
    unsigned short* wob = (unsigned short*)(ws + (size_t)(14 << 20));
    unsigned short* qb  = (unsigned short*)(ws + (size_t)(16 << 20));
    unsigned short* kb  = (unsigned short*)(ws + (size_t)(24 << 20));
    unsigned short* vtb = (unsigned short*)(ws + (size_t)(32 << 20));
    unsigned short* aob = (unsigned short*)(ws + (size_t)(40 << 20));

    cvt_bf16<<<4096, 256, 0, stream>>>(x,  xb,  M * D);
    cvt_bf16<<<1024, 256, 0, stream>>>(wq, wqb, D * D);
    cvt_bf16<<<1024, 256, 0, stream>>>(wk, wkb, D * D);
    cvt_bf16<<<1024, 256, 0, stream>>>(wv, wvb, D * D);
    cvt_bf16<<<1024, 256, 0, stream>>>(wo, wob, D * D);

    gemm_qkv<<<dim3(256, 3), 256, 0, stream>>>(xb, wqb, wkb, wvb, qb, kb, vtb);
    flash_attn<<<1024, 256, 0, stream>>>(qb, kb, vtb, aob);
    out_gemm<<<256, 256, 0, stream>>>(aob, wob, (float*)d_out);
}

// Round 3
// 151.205 us; speedup vs baseline: 4.6484x; 2.0518x over previous
//
#include <hip/hip_runtime.h>

#define LB __launch_bounds__(256)

typedef __bf16 bf16x8 __attribute__((ext_vector_type(8)));
typedef float f32x4 __attribute__((ext_vector_type(4)));
typedef float f32x16 __attribute__((ext_vector_type(16)));
typedef unsigned int u32;

constexpr int B = 2, S = 2048, D = 1024, H = 16, DK = 64;
constexpr int M = B * S;   // 4096 tokens
constexpr int K = D;       // 1024 inner dim for projections

__device__ __forceinline__ unsigned short f2bf(float f) {
    union { float f; unsigned u; } v; v.f = f;
    unsigned r = v.u + 0x7fffu + ((v.u >> 16) & 1u);
    return (unsigned short)(r >> 16);
}

__device__ __forceinline__ u32 pk2bf(float lo, float hi) {
    union { __bf16 h[2]; u32 w; } u;
    u.h[0] = (__bf16)lo; u.h[1] = (__bf16)hi;
    return u.w;
}

__device__ __forceinline__ void gld_lds16(const unsigned short* g, unsigned short* l) {
    __builtin_amdgcn_global_load_lds(
        (const __attribute__((address_space(1))) unsigned int*)g,
        (__attribute__((address_space(3))) unsigned int*)l, 16, 0, 0);
}

// ---- fp32 -> bf16 convert ----
__global__ LB void cvt_bf16(const float* __restrict__ src,
                            unsigned short* __restrict__ dst, int n) {
    int i = (blockIdx.x * 256 + threadIdx.x) * 4;
    if (i >= n) return;
    float4 f = *reinterpret_cast<const float4*>(src + i);
    ushort4 o;
    o.x = f2bf(f.x); o.y = f2bf(f.y); o.z = f2bf(f.z); o.w = f2bf(f.w);
    *reinterpret_cast<ushort4*>(dst + i) = o;
}

// ---- fused QKV projection (unchanged from R2) ----
__global__ LB void gemm_qkv(const unsigned short* __restrict__ A,
                            const unsigned short* __restrict__ wqb,
                            const unsigned short* __restrict__ wkb,
                            const unsigned short* __restrict__ wvb,
                            unsigned short* __restrict__ qo,
                            unsigned short* __restrict__ ko,
                            unsigned short* __restrict__ vo) {
    __shared__ __align__(16) unsigned short lA[128 * 32];
    __shared__ __align__(16) unsigned short lB[128 * 32];
    const int z = blockIdx.y;
    const unsigned short* W = (z == 0) ? wqb : ((z == 1) ? wkb : wvb);
    int m0 = (blockIdx.x >> 3) * 128;
    int n0 = (blockIdx.x & 7) * 128;
    int t = threadIdx.x;
    int w = t >> 6, lane = t & 63;
    int r = lane & 15, g = lane >> 4;
    int wr = w >> 1, wc = w & 1;
    int rowT = t >> 2, colOff = (t & 3) * 8;

    f32x4 acc[4][4];
#pragma unroll
    for (int mi = 0; mi < 4; ++mi)
#pragma unroll
        for (int ni = 0; ni < 4; ++ni) acc[mi][ni] = f32x4{0.f, 0.f, 0.f, 0.f};

    for (int k0 = 0; k0 < K; k0 += 32) {
        gld_lds16(A + (size_t)(m0 + rowT) * K + k0 + colOff,      lA + (w * 64) * 8);
        gld_lds16(A + (size_t)(m0 + 64 + rowT) * K + k0 + colOff, lA + (256 + w * 64) * 8);
        gld_lds16(W + (size_t)(n0 + rowT) * K + k0 + colOff,      lB + (w * 64) * 8);
        gld_lds16(W + (size_t)(n0 + 64 + rowT) * K + k0 + colOff, lB + (256 + w * 64) * 8);
        __syncthreads();
        bf16x8 af[4], bfr[4];
#pragma unroll
        for (int mi = 0; mi < 4; ++mi)
            af[mi] = *reinterpret_cast<const bf16x8*>(&lA[(wr * 64 + mi * 16 + r) * 32 + g * 8]);
#pragma unroll
        for (int ni = 0; ni < 4; ++ni)
            bfr[ni] = *reinterpret_cast<const bf16x8*>(&lB[(wc * 64 + ni * 16 + r) * 32 + g * 8]);
#pragma unroll
        for (int mi = 0; mi < 4; ++mi)
#pragma unroll
            for (int ni = 0; ni < 4; ++ni)
                acc[mi][ni] = __builtin_amdgcn_mfma_f32_16x16x32_bf16(af[mi], bfr[ni], acc[mi][ni], 0, 0, 0);
        __syncthreads();
    }

    const float QSCALE = 0.125f * 1.44269504088896341f;
    float scale = (z == 0) ? QSCALE : 1.0f;
    unsigned short* dst = (z == 0) ? qo : ((z == 1) ? ko : vo);
#pragma unroll
    for (int mi = 0; mi < 4; ++mi)
#pragma unroll
        for (int ni = 0; ni < 4; ++ni)
#pragma unroll
            for (int j = 0; j < 4; ++j) {
                int row = m0 + wr * 64 + mi * 16 + g * 4 + j;
                int col = n0 + wc * 64 + ni * 16 + r;
                int b = row >> 11, s = row & (S - 1);
                int h = col >> 6, dk = col & 63;
                unsigned short val = f2bf(acc[mi][ni][j] * scale);
                if (z < 2) dst[((size_t)(b * H + h) * S + s) * DK + dk] = val;
                else       dst[((size_t)(b * H + h) * DK + dk) * S + s] = val;
            }
}

// ---- output projection (unchanged from R2) ----
__global__ LB void out_gemm(const unsigned short* __restrict__ A,
                            const unsigned short* __restrict__ W,
                            float* __restrict__ out) {
    __shared__ __align__(16) unsigned short lA[128 * 32];
    __shared__ __align__(16) unsigned short lB[128 * 32];
    int m0 = (blockIdx.x >> 3) * 128;
    int n0 = (blockIdx.x & 7) * 128;
    int t = threadIdx.x;
    int w = t >> 6, lane = t & 63;
    int r = lane & 15, g = lane >> 4;
    int wr = w >> 1, wc = w & 1;
    int rowT = t >> 2, colOff = (t & 3) * 8;

    f32x4 acc[4][4];
#pragma unroll
    for (int mi = 0; mi < 4; ++mi)
#pragma unroll
        for (int ni = 0; ni < 4; ++ni) acc[mi][ni] = f32x4{0.f, 0.f, 0.f, 0.f};

    for (int k0 = 0; k0 < K; k0 += 32) {
        gld_lds16(A + (size_t)(m0 + rowT) * K + k0 + colOff,      lA + (w * 64) * 8);
        gld_lds16(A + (size_t)(m0 + 64 + rowT) * K + k0 + colOff, lA + (256 + w * 64) * 8);
        gld_lds16(W + (size_t)(n0 + rowT) * K + k0 + colOff,      lB + (w * 64) * 8);
        gld_lds16(W + (size_t)(n0 + 64 + rowT) * K + k0 + colOff, lB + (256 + w * 64) * 8);
        __syncthreads();
        bf16x8 af[4], bfr[4];
#pragma unroll
        for (int mi = 0; mi < 4; ++mi)
            af[mi] = *reinterpret_cast<const bf16x8*>(&lA[(wr * 64 + mi * 16 + r) * 32 + g * 8]);
#pragma unroll
        for (int ni = 0; ni < 4; ++ni)
            bfr[ni] = *reinterpret_cast<const bf16x8*>(&lB[(wc * 64 + ni * 16 + r) * 32 + g * 8]);
#pragma unroll
        for (int mi = 0; mi < 4; ++mi)
#pragma unroll
            for (int ni = 0; ni < 4; ++ni)
                acc[mi][ni] = __builtin_amdgcn_mfma_f32_16x16x32_bf16(af[mi], bfr[ni], acc[mi][ni], 0, 0, 0);
        __syncthreads();
    }

#pragma unroll
    for (int mi = 0; mi < 4; ++mi)
#pragma unroll
        for (int ni = 0; ni < 4; ++ni)
#pragma unroll
            for (int j = 0; j < 4; ++j) {
                int row = m0 + wr * 64 + mi * 16 + g * 4 + j;
                int col = n0 + wc * 64 + ni * 16 + r;
                out[(size_t)row * D + col] = acc[mi][ni][j];
            }
}

// ---- causal flash attention, swapped-operand 32x32 MFMA ----
// q,k: [B,H,S,DK] bf16 (q pre-scaled by 0.125*log2e), vt: [B,H,DK,S] bf16
// 4 waves x 32 q-rows = 128 q-rows/block; KVBLK=64; K/V LDS-staged, swizzled, dbuf.
__global__ LB void flash_attn(const unsigned short* __restrict__ q,
                              const unsigned short* __restrict__ kmat,
                              const unsigned short* __restrict__ vt,
                              unsigned short* __restrict__ ao) {
    __shared__ __align__(16) unsigned short lds[2][2][4096];  // [buf][K/V][64x64]
    int bid = blockIdx.x;                 // 512 blocks
    int uu = bid >> 8, v = bid & 255;
    int bh = v >> 3, tq = v & 7;
    int qi = uu ? (15 - tq) : tq;         // pair qi with 15-qi for causal balance
    int b = bh >> 4, hd = bh & 15;
    int q0 = qi << 7;
    int nt = 2 * qi + 2;

    int t = threadIdx.x, w = t >> 6, l = t & 63;
    int q5 = l & 31, hl = l >> 5, l7 = l & 7;
    int qg0w = q0 + w * 32;
    int qglob = qg0w + q5;
    int qwLast = qg0w + 31;

    const unsigned short* qp = q    + (size_t)(b * H + hd) * S * DK;
    const unsigned short* kp = kmat + (size_t)(b * H + hd) * S * DK;
    const unsigned short* vp = vt   + (size_t)(b * H + hd) * DK * S;

    // staging mapping: thread t covers LDS bytes [t*16, t*16+16) of each 8KB tile
    int srow = t >> 3;                       // 0..31 (row within 32-row half)
    int ssc  = (((t & 7) << 4) ^ ((srow & 7) << 4)) >> 1;  // pre-swizzled src elem col

    auto stage = [&](int buf, int kb) {
        char* Kd = (char*)&lds[buf][0][0] + (w << 10);
        char* Vd = (char*)&lds[buf][1][0] + (w << 10);
#pragma unroll
        for (int i = 0; i < 2; ++i) {
            gld_lds16(kp + (size_t)(kb + i * 32 + srow) * DK + ssc,
                      (unsigned short*)(Kd + i * 4096));
            gld_lds16(vp + (size_t)(i * 32 + srow) * S + kb + ssc,
                      (unsigned short*)(Vd + i * 4096));
        }
    };

    bf16x8 qf[4];
#pragma unroll
    for (int dsi = 0; dsi < 4; ++dsi)
        qf[dsi] = *reinterpret_cast<const bf16x8*>(qp + (size_t)qglob * DK + dsi * 16 + hl * 8);

    const f32x16 z16 = {0,0,0,0,0,0,0,0,0,0,0,0,0,0,0,0};
    f32x16 acc0 = z16, acc1 = z16;
    float mr = -1e30f, lr = 0.f;

    stage(0, 0);
    __syncthreads();

    int cur = 0;
    for (int it = 0; it < nt; ++it) {
        int kb = it << 6;
        if (it + 1 < nt) stage(cur ^ 1, (it + 1) << 6);
        if (kb <= qwLast) {
            const char* Kb = (const char*)&lds[cur][0][0];
            const char* Vb = (const char*)&lds[cur][1][0];
            f32x16 st0 = z16, st1 = z16;
            __builtin_amdgcn_s_setprio(1);
#pragma unroll
            for (int dsi = 0; dsi < 4; ++dsi) {
                int colb = (dsi * 32 + hl * 16) ^ (l7 << 4);
                bf16x8 k0 = *reinterpret_cast<const bf16x8*>(Kb + q5 * 128 + colb);
                bf16x8 k1 = *reinterpret_cast<const bf16x8*>(Kb + (32 + q5) * 128 + colb);
                st0 = __builtin_amdgcn_mfma_f32_32x32x16_bf16(k0, qf[dsi], st0, 0, 0, 0);
                st1 = __builtin_amdgcn_mfma_f32_32x32x16_bf16(k1, qf[dsi], st1, 0, 0, 0);
            }
            __builtin_amdgcn_s_setprio(0);
            // causal masking (wave-uniform guards; only tail tiles pay)
            if (kb + 31 > qg0w) {
#pragma unroll
                for (int r = 0; r < 16; ++r) {
                    int kv = kb + (r & 3) + 8 * (r >> 2) + 4 * hl;
                    st0[r] = (kv <= qglob) ? st0[r] : -1e30f;
                }
            }
            if (kb + 63 > qg0w) {
#pragma unroll
                for (int r = 0; r < 16; ++r) {
                    int kv = kb + 32 + (r & 3) + 8 * (r >> 2) + 4 * hl;
                    st1[r] = (kv <= qglob) ? st1[r] : -1e30f;
                }
            }
            // online softmax: in-lane reduce + one cross-half shuffle
            float tm = -1e30f;
#pragma unroll
            for (int r = 0; r < 16; ++r) tm = fmaxf(tm, fmaxf(st0[r], st1[r]));
            tm = fmaxf(tm, __shfl_xor(tm, 32));
            float mnew = fmaxf(mr, tm);
            float alpha = exp2f(mr - mnew);
            mr = mnew;
            float ps = 0.f;
#pragma unroll
            for (int r = 0; r < 16; ++r) { st0[r] = exp2f(st0[r] - mnew); ps += st0[r]; }
#pragma unroll
            for (int r = 0; r < 16; ++r) { st1[r] = exp2f(st1[r] - mnew); ps += st1[r]; }
            ps += __shfl_xor(ps, 32);
            lr = lr * alpha + ps;
            acc0 *= alpha;
            acc1 *= alpha;
            // pack P to bf16 and build kv-contiguous fragments (1 swap per 16-kv slice)
            u32 pk[2][8];
#pragma unroll
            for (int rg = 0; rg < 4; ++rg) {
                pk[0][2*rg]   = pk2bf(st0[4*rg],   st0[4*rg+1]);
                pk[0][2*rg+1] = pk2bf(st0[4*rg+2], st0[4*rg+3]);
                pk[1][2*rg]   = pk2bf(st1[4*rg],   st1[4*rg+1]);
                pk[1][2*rg+1] = pk2bf(st1[4*rg+2], st1[4*rg+3]);
            }
            union PF { bf16x8 vv; u32 w[4]; } pf[4];
#pragma unroll
            for (int ti = 0; ti < 2; ++ti)
#pragma unroll
                for (int s = 0; s < 2; ++s) {
                    u32 s0 = hl ? pk[ti][4*s]   : pk[ti][4*s+2];
                    u32 s1 = hl ? pk[ti][4*s+1] : pk[ti][4*s+3];
                    u32 r0 = (u32)__shfl_xor((int)s0, 32);
                    u32 r1 = (u32)__shfl_xor((int)s1, 32);
                    PF f;
                    f.w[0] = hl ? r0 : pk[ti][4*s];
                    f.w[1] = hl ? r1 : pk[ti][4*s+1];
                    f.w[2] = hl ? pk[ti][4*s+2] : r0;
                    f.w[3] = hl ? pk[ti][4*s+3] : r1;
                    pf[ti*2+s] = f;
                }
            // PV: O^T = V^T x P^T (alpha-rescale is lane-uniform)
            __builtin_amdgcn_s_setprio(1);
#pragma unroll
            for (int ks = 0; ks < 4; ++ks) {
                int colv = (ks * 32 + hl * 16) ^ (l7 << 4);
                bf16x8 vf0 = *reinterpret_cast<const bf16x8*>(Vb + q5 * 128 + colv);
                bf16x8 vf1 = *reinterpret_cast<const bf16x8*>(Vb + (32 + q5) * 128 + colv);
                acc0 = __builtin_amdgcn_mfma_f32_32x32x16_bf16(vf0, pf[ks].vv, acc0, 0, 0, 0);
                acc1 = __builtin_amdgcn_mfma_f32_32x32x16_bf16(vf1, pf[ks].vv, acc1, 0, 0, 0);
            }
            __builtin_amdgcn_s_setprio(0);
        }
        __syncthreads();
        cur ^= 1;
    }

    float inv = 1.0f / lr;
    size_t obase = ((size_t)(b * S + qglob)) * D + hd * DK;
#pragma unroll
    for (int rg = 0; rg < 4; ++rg) {
        uint2 wd;
        wd.x = pk2bf(acc0[4*rg]   * inv, acc0[4*rg+1] * inv);
        wd.y = pk2bf(acc0[4*rg+2] * inv, acc0[4*rg+3] * inv);
        *reinterpret_cast<uint2*>(ao + obase + rg * 8 + hl * 4) = wd;
        uint2 we;
        we.x = pk2bf(acc1[4*rg]   * inv, acc1[4*rg+1] * inv);
        we.y = pk2bf(acc1[4*rg+2] * inv, acc1[4*rg+3] * inv);
        *reinterpret_cast<uint2*>(ao + obase + 32 + rg * 8 + hl * 4) = we;
    }
}

extern "C" void kernel_launch(void* const* d_in, const int* in_sizes, int n_in,
                              void* d_out, int out_size, void* d_ws, size_t ws_size,
                              hipStream_t stream) {
    const float* x  = (const float*)d_in[0];
    const float* wq = (const float*)d_in[1];
    const float* wk = (const float*)d_in[2];
    const float* wv = (const float*)d_in[3];
    const float* wo = (const float*)d_in[4];
    char* ws = (char*)d_ws;
    unsigned short* xb  = (unsigned short*)(ws);
    unsigned short* wqb = (unsigned short*)(ws + (size_t)(8  << 20));
    unsigned short* wkb = (unsigned short*)(ws + (size_t)(10 << 20));
    unsigned short* wvb = (unsigned short*)(ws + (size_t)(12 << 20));
    unsigned short* wob = (unsigned short*)(ws + (size_t)(14 << 20));
    unsigned short* qb  = (unsigned short*)(ws + (size_t)(16 << 20));
    unsigned short* kb  = (unsigned short*)(ws + (size_t)(24 << 20));
    unsigned short* vtb = (unsigned short*)(ws + (size_t)(32 << 20));
    unsigned short* aob = (unsigned short*)(ws + (size_t)(40 << 20));

    cvt_bf16<<<4096, 256, 0, stream>>>(x,  xb,  M * D);
    cvt_bf16<<<1024, 256, 0, stream>>>(wq, wqb, D * D);
    cvt_bf16<<<1024, 256, 0, stream>>>(wk, wkb, D * D);
    cvt_bf16<<<1024, 256, 0, stream>>>(wv, wvb, D * D);
    cvt_bf16<<<1024, 256, 0, stream>>>(wo, wob, D * D);

    gemm_qkv<<<dim3(256, 3), 256, 0, stream>>>(xb, wqb, wkb, wvb, qb, kb, vtb);
    flash_attn<<<512, 256, 0, stream>>>(qb, kb, vtb, aob);
    out_gemm<<<256, 256, 0, stream>>>(aob, wob, (float*)d_out);
}